// Round 3
// baseline (235.178 us; speedup 1.0000x reference)
//
#include <hip/hip_runtime.h>

// BrewCnnLayer fused, v3: one 128-thread block (2 waves) per image.
//   conv1: W1 (10,1,7,7) VALID -> (10,22,22); relu + ratio1
//   conv2: W2 (10,10,5,5) VALID -> (10,18,18); relu + ratio2
// out = [ h2 (b*3240) | rat1 (b*4840) | rat2 (b*3240) ]  (f32)
//
// Key structure: thread = (out-row, col-group), accumulating ALL 10 output
// channels (acc[10][G]). Weight indices are thread-uniform -> compiler emits
// s_load (scalar cache, SMEM pipe) -> zero LDS/VMEM cost for weights, and
// each LDS data float feeds 10x more FMAs than an oc-per-thread layout.
// LDS = image (3.1 KB) + h1 (21.1 KB) = 24.3 KB -> 6 blocks/CU, 12 waves/CU.
// fp32 vector math throughout (no fp32 MFMA on CDNA4; bf16 flips ratio signs).

#define THREADS 128

__global__ __launch_bounds__(THREADS, 3) void brewcnn_fused(
    const float* __restrict__ x,    // (nimg, 784)
    const float* __restrict__ Wa,   // (10, 49)
    const float* __restrict__ Wb,   // (10, 250)
    float* __restrict__ out,
    int nimg)
{
    __shared__ __align__(16) float s_x[28 * 28];        // 3136 B
    __shared__ __align__(16) float s_h[10][22 * 24];    // 21120 B (rows padded 22->24)

    const int img = blockIdx.x;
    const int tid = threadIdx.x;

    // ---- stage image into LDS (float4, coalesced) ----
    {
        const float4* xin = reinterpret_cast<const float4*>(x + img * 784);
        float4* sx4 = reinterpret_cast<float4*>(s_x);
        if (tid < 98) { sx4[tid] = xin[tid]; sx4[tid + 98] = xin[tid + 98]; }
    }
    __syncthreads();

    const int h2_base = img * 3240;
    const int r1_base = nimg * 3240 + img * 4840;
    const int r2_base = nimg * 8080 + img * 3240;

    // ---- conv1: task = (row, col-group of 5), 22 rows x 5 groups = 110 ----
    // group starts {0,5,10,15,17}: groups 3&4 overlap cols 17-19; duplicate
    // threads compute bit-identical values (same FMA order) -> benign dup writes.
    if (tid < 110) {
        const int row = tid / 5;
        const int g   = tid - row * 5;
        const int c   = (g < 4) ? 5 * g : 17;

        float acc[10][5];
#pragma unroll
        for (int oc = 0; oc < 10; ++oc)
#pragma unroll
            for (int k = 0; k < 5; ++k) acc[oc][k] = 0.0f;

#pragma unroll 1
        for (int ky = 0; ky < 7; ++ky) {
            float in[11];
            const float* rp = s_x + (row + ky) * 28 + c;
#pragma unroll
            for (int j = 0; j < 11; ++j) in[j] = rp[j];

#pragma unroll
            for (int oc = 0; oc < 10; ++oc) {
                const float* wp = Wa + oc * 49 + ky * 7;   // uniform -> s_load
#pragma unroll
                for (int kx = 0; kx < 7; ++kx) {
                    const float w = wp[kx];
#pragma unroll
                    for (int k = 0; k < 5; ++k)
                        acc[oc][k] = fmaf(in[k + kx], w, acc[oc][k]);
                }
            }
        }

        // epilogue: relu -> LDS (h1), ratio1 -> global
#pragma unroll
        for (int oc = 0; oc < 10; ++oc) {
            float* hdst = &s_h[oc][row * 24 + c];
            float* r1p  = out + r1_base + oc * 484 + row * 22 + c;
#pragma unroll
            for (int k = 0; k < 5; ++k) {
                const float h = acc[oc][k];
                hdst[k] = h > 0.0f ? h : 0.0f;
                r1p[k]  = h > 0.0f ? 1.0f : 0.0f;
            }
        }
    }
    __syncthreads();

    // ---- conv2: task = (row, col-group of 3), 18 rows x 6 groups = 108 ----
    if (tid < 108) {
        const int row = tid / 6;
        const int c   = 3 * (tid - row * 6);

        float acc[10][3];
#pragma unroll
        for (int oc = 0; oc < 10; ++oc)
#pragma unroll
            for (int k = 0; k < 3; ++k) acc[oc][k] = 0.0f;

#pragma unroll 1
        for (int ic = 0; ic < 10; ++ic) {
            const float* hb = &s_h[ic][row * 24 + c];
            const float* wi = Wb + ic * 25;
#pragma unroll
            for (int ky = 0; ky < 5; ++ky) {
                float in[7];
                const float* rp = hb + ky * 24;
#pragma unroll
                for (int j = 0; j < 7; ++j) in[j] = rp[j];

#pragma unroll
                for (int oc = 0; oc < 10; ++oc) {
                    const float* wp = wi + oc * 250 + ky * 5;  // uniform -> s_load
#pragma unroll
                    for (int kx = 0; kx < 5; ++kx) {
                        const float w = wp[kx];
#pragma unroll
                        for (int k = 0; k < 3; ++k)
                            acc[oc][k] = fmaf(in[k + kx], w, acc[oc][k]);
                    }
                }
            }
        }

        // epilogue: h2 + ratio2 -> global
#pragma unroll
        for (int oc = 0; oc < 10; ++oc) {
            float* h2p = out + h2_base + oc * 324 + row * 18 + c;
            float* r2p = out + r2_base + oc * 324 + row * 18 + c;
#pragma unroll
            for (int k = 0; k < 3; ++k) {
                const float h = acc[oc][k];
                h2p[k] = h > 0.0f ? h : 0.0f;
                r2p[k] = h > 0.0f ? 1.0f : 0.0f;
            }
        }
    }
}

extern "C" void kernel_launch(void* const* d_in, const int* in_sizes, int n_in,
                              void* d_out, int out_size, void* d_ws, size_t ws_size,
                              hipStream_t stream) {
    const float* x  = (const float*)d_in[0];
    const float* Wa = (const float*)d_in[1];
    const float* Wb = (const float*)d_in[2];
    float* out = (float*)d_out;
    const int nimg = in_sizes[0] / 784;

    brewcnn_fused<<<nimg, THREADS, 0, stream>>>(x, Wa, Wb, out, nimg);
}